// Round 6
// baseline (495.685 us; speedup 1.0000x reference)
//
#include <hip/hip_runtime.h>
#include <hip/hip_bf16.h>
#include <math.h>

// SparseMLP: W=8 experts, per w: out = gelu(X @ W1 + b1) @ W2 + b2
// Round 6: fat-wave GEMM. BM=BN=256, BK=64, 256 thr = 4 waves (2x2), wave
// tile 128x128 (square => 256 B LDS-read per MFMA, 1.5x better than 128x64).
// 1 wave/SIMD, ~410 VGPR (launch_bounds(256,1); acc 256 + frags 128).
// ONE barrier + ONE vmcnt(0) per K-tile; NO intra-tile barriers — the
// compiler's counted lgkmcnt scheduling interleaves ds_reads under the
// 64-MFMA clusters within each wave (m97 evidence). Serialized-model bound:
// MFMA 2483 + LDS 1024 cyc per K-tile => >62% util achievable.
// LDS [row][128B] linear rows, XOR swizzle byte^=(row&7)<<4, staged by
// global_load_lds with inverse-swizzled global source (rule #21, 0-conflict
// verified in R4/R5). Expert pinned to XCD via bid%8.

typedef float f32x4 __attribute__((ext_vector_type(4)));
typedef short bf16x8 __attribute__((ext_vector_type(8)));
typedef short bf16x4 __attribute__((ext_vector_type(4)));
typedef unsigned short u16;

#define NW 8
#define MDIM 2048   // BHS*SEQ
#define HDIM 2048
#define FFN  1024

static __device__ __forceinline__ u16 f32_to_bf16_rn(float f) {
  union { float f; unsigned u; } v; v.f = f;
  unsigned r = v.u + 0x7FFF + ((v.u >> 16) & 1);
  return (u16)(r >> 16);
}

static __device__ __forceinline__ void gload_lds16(const void* g, void* l) {
  __builtin_amdgcn_global_load_lds(
      (const __attribute__((address_space(1))) void*)g,
      (__attribute__((address_space(3))) void*)l, 16, 0, 0);
}

// X (NW*MDIM*HDIM f32) -> bf16, vectorized 4-wide
__global__ void convert_bf16_kernel(const float* __restrict__ in,
                                    u16* __restrict__ out) {
  size_t i = (size_t)blockIdx.x * blockDim.x + threadIdx.x;  // f32x4 index
  f32x4 v = ((const f32x4*)in)[i];
  bf16x4 p;
  p[0] = (short)f32_to_bf16_rn(v.x);
  p[1] = (short)f32_to_bf16_rn(v.y);
  p[2] = (short)f32_to_bf16_rn(v.z);
  p[3] = (short)f32_to_bf16_rn(v.w);
  ((bf16x4*)out)[i] = p;
}

// in: (NW, R, C) f32  ->  out: (NW, C, R) bf16 (convert + transpose), 64x64 tile
__global__ void convert_transpose_kernel(const float* __restrict__ in,
                                         u16* __restrict__ out, int R, int C) {
  __shared__ u16 tile[64][68];
  int w = blockIdx.z;
  int c0 = blockIdx.x * 64, r0 = blockIdx.y * 64;
  int t = threadIdx.x;  // 256 threads
  const float* ip = in + (size_t)w * R * C;
  u16* op = out + (size_t)w * C * R;
  int tr = t >> 4;       // 0..15
  int tc4 = (t & 15) * 4;
#pragma unroll
  for (int j = 0; j < 4; ++j) {
    int r = tr + j * 16;
    f32x4 v = *(const f32x4*)(ip + (size_t)(r0 + r) * C + c0 + tc4);
    tile[r][tc4 + 0] = f32_to_bf16_rn(v.x);
    tile[r][tc4 + 1] = f32_to_bf16_rn(v.y);
    tile[r][tc4 + 2] = f32_to_bf16_rn(v.z);
    tile[r][tc4 + 3] = f32_to_bf16_rn(v.w);
  }
  __syncthreads();
#pragma unroll
  for (int j = 0; j < 4; ++j) {
    int c = tr + j * 16;
    bf16x4 p;
    p[0] = (short)tile[tc4 + 0][c];
    p[1] = (short)tile[tc4 + 1][c];
    p[2] = (short)tile[tc4 + 2][c];
    p[3] = (short)tile[tc4 + 3][c];
    *(bf16x4*)(op + (size_t)(c0 + c) * R + r0 + tc4) = p;
  }
}

// K-tile buffer (64KB): A [256 rows][128B] @0, B [256 rows][128B] @32768.
// 256 threads stage 32 rows (4KB) per sweep; 8 sweeps A + 8 sweeps B.
#define STAGE_ALL(dst, tt)                                                    \
  do {                                                                        \
    const size_t kb_ = (size_t)(tt) * 128;                                    \
    _Pragma("unroll") for (int s_ = 0; s_ < 8; ++s_)                          \
        gload_lds16(gAs + (size_t)s_ * 32 * rowK + kb_,                       \
                    (dst) + s_ * 4096 + tid * 16);                            \
    _Pragma("unroll") for (int s_ = 0; s_ < 8; ++s_)                          \
        gload_lds16(gBs + (size_t)s_ * 32 * rowK + kb_,                       \
                    (dst) + 32768 + s_ * 4096 + tid * 16);                    \
  } while (0)

// C = op(A @ B^T + bias); A: (NW,M,K) bf16; Bt: (NW,N,K) bf16.
template <bool GELU, bool C_F32>
__global__ __launch_bounds__(256, 1) void mlp_gemm(
    const u16* __restrict__ A, const u16* __restrict__ Bt,
    const float* __restrict__ bias, void* __restrict__ Cptr,
    int M, int N, int K, int nN) {
  __shared__ __align__(16) char lds[131072];

  const int bid = blockIdx.x;
  const int w = bid & 7;            // expert -> pinned to XCD bid%8
  const int jb = bid >> 3;
  const int m0 = (jb / nN) * 256;
  const int n0 = (jb % nN) * 256;

  const int tid = threadIdx.x;
  const int wid = tid >> 6, lane = tid & 63;
  const int wr = wid >> 1, wcn = wid & 1;   // 2 M-waves x 2 N-waves
  const int qa = lane >> 4, ra = lane & 15;

  const u16* ap = A + (size_t)w * M * K;
  const u16* btp = Bt + (size_t)w * N * K;
  const float* bp = bias + (size_t)w * N;

  const size_t rowK = (size_t)K * 2;        // bytes per K-row
  // staging source (inverse-swizzled): row = base + s*32 + (tid>>3)
  const int colb = ((tid & 7) * 16) ^ (((tid >> 3) & 7) << 4);
  const char* gAs = (const char*)ap + (size_t)(m0 + (tid >> 3)) * rowK + colb;
  const char* gBs = (const char*)btp + (size_t)(n0 + (tid >> 3)) * rowK + colb;

  // fragment-read constants
  const int csw = (qa * 16) ^ ((ra & 7) << 4);  // + (kk<<6) XOR for k-half
  const int arow = wr * 128 + ra;               // + i*16
  const int brow = wcn * 128 + ra;              // + j*16

  f32x4 acc[8][8];
#pragma unroll
  for (int i = 0; i < 8; ++i)
#pragma unroll
    for (int j = 0; j < 8; ++j)
#pragma unroll
      for (int r = 0; r < 4; ++r) acc[i][j][r] = 0.0f;

  const int NT = K >> 6;   // 64-wide K-tiles (GEMM1: 32, GEMM2: 16)
  char* cb = lds;
  char* nb = lds + 65536;

  // prologue: stage tile 0
  STAGE_ALL(cb, 0);
  asm volatile("s_waitcnt vmcnt(0)" ::: "memory");
  __builtin_amdgcn_s_barrier();
  __builtin_amdgcn_sched_barrier(0);

  for (int t = 0; t < NT; ++t) {
    if (t + 1 < NT) STAGE_ALL(nb, t + 1);   // 16 gloads, issued first
    __builtin_amdgcn_sched_barrier(0);      // pin stage-issue before compute

#pragma unroll
    for (int kk = 0; kk < 2; ++kk) {
      bf16x8 afr[8], bfr[8];
#pragma unroll
      for (int i = 0; i < 8; ++i)
        afr[i] = *(const bf16x8*)(cb + (size_t)(arow + i * 16) * 128 +
                                  (csw ^ (kk << 6)));
#pragma unroll
      for (int j = 0; j < 8; ++j)
        bfr[j] = *(const bf16x8*)(cb + 32768 + (size_t)(brow + j * 16) * 128 +
                                  (csw ^ (kk << 6)));
      __builtin_amdgcn_s_setprio(1);
#pragma unroll
      for (int i = 0; i < 8; ++i)
#pragma unroll
        for (int j = 0; j < 8; ++j)
          acc[i][j] = __builtin_amdgcn_mfma_f32_16x16x32_bf16(
              afr[i], bfr[j], acc[i][j], 0, 0, 0);
      __builtin_amdgcn_s_setprio(0);
    }

    asm volatile("s_waitcnt vmcnt(0)" ::: "memory");  // tile t+1 landed
    __builtin_amdgcn_s_barrier();                     // all reads of cb done
    __builtin_amdgcn_sched_barrier(0);                // nothing crosses
    char* tp = cb; cb = nb; nb = tp;
  }

  // epilogue: + bias, optional exact GELU, store
#pragma unroll
  for (int i = 0; i < 8; ++i) {
#pragma unroll
    for (int j = 0; j < 8; ++j) {
      int col = n0 + wcn * 128 + j * 16 + ra;
      float bv = bp[col];
#pragma unroll
      for (int r = 0; r < 4; ++r) {
        int row = m0 + wr * 128 + i * 16 + qa * 4 + r;
        float v = acc[i][j][r] + bv;
        if (GELU) v = 0.5f * v * (1.0f + erff(v * 0.70710678118654752f));
        if (C_F32)
          ((float*)Cptr)[(size_t)w * M * N + (size_t)row * N + col] = v;
        else
          ((u16*)Cptr)[(size_t)w * M * N + (size_t)row * N + col] =
              f32_to_bf16_rn(v);
      }
    }
  }
}

__global__ void bias_out_kernel(const float* __restrict__ b2,
                                float* __restrict__ outb) {
  int i = blockIdx.x * 256 + threadIdx.x;
  if (i < NW * HDIM) outb[i] = b2[i];
}

extern "C" void kernel_launch(void* const* d_in, const int* in_sizes, int n_in,
                              void* d_out, int out_size, void* d_ws,
                              size_t ws_size, hipStream_t stream) {
  const float* hs = (const float*)d_in[0];  // (8,2,1024,2048) f32
  const float* w1 = (const float*)d_in[1];  // (8,2048,1024) f32
  const float* b1 = (const float*)d_in[2];  // (8,1,1024) f32
  const float* w2 = (const float*)d_in[3];  // (8,1024,2048) f32
  const float* b2 = (const float*)d_in[4];  // (8,2048) f32

  // ws (u16): W1t (8,1024,2048) | W2t (8,2048,1024) | inter (8,2048,1024) | Xb (8,2048,2048)
  u16* W1t = (u16*)d_ws;
  u16* W2t = W1t + (size_t)NW * FFN * HDIM;
  u16* inter = W2t + (size_t)NW * HDIM * FFN;
  u16* XbWs = inter + (size_t)NW * MDIM * FFN;
  size_t need = ((size_t)NW * FFN * HDIM * 2 + (size_t)NW * MDIM * FFN +
                 (size_t)NW * MDIM * HDIM) * sizeof(u16);
  u16* Xb = (ws_size >= need) ? XbWs : (u16*)d_out;

  convert_bf16_kernel<<<dim3(NW * MDIM * HDIM / 4 / 256), 256, 0, stream>>>(hs, Xb);
  convert_transpose_kernel<<<dim3(FFN / 64, HDIM / 64, NW), 256, 0, stream>>>(
      w1, W1t, HDIM, FFN);
  convert_transpose_kernel<<<dim3(HDIM / 64, FFN / 64, NW), 256, 0, stream>>>(
      w2, W2t, FFN, HDIM);

  // inter = gelu(X @ W1 + b1)  [bf16]  M=2048 N=1024 K=2048 -> 256 blocks (1/CU)
  mlp_gemm<true, false>
      <<<dim3(NW * (MDIM / 256) * (FFN / 256)), 256, 0, stream>>>(
          Xb, W1t, b1, inter, MDIM, FFN, HDIM, FFN / 256);
  // out = inter @ W2 + b2  [f32]  M=2048 N=2048 K=1024 -> 512 blocks
  mlp_gemm<false, true>
      <<<dim3(NW * (MDIM / 256) * (HDIM / 256)), 256, 0, stream>>>(
          inter, W2t, b2, d_out, MDIM, HDIM, FFN, HDIM / 256);

  float* outb = (float*)d_out + (size_t)NW * MDIM * HDIM;
  bias_out_kernel<<<dim3((NW * HDIM + 255) / 256), 256, 0, stream>>>(b2, outb);
}

// Round 7
// 279.133 us; speedup vs baseline: 1.7758x; 1.7758x over previous
//
#include <hip/hip_runtime.h>
#include <hip/hip_bf16.h>
#include <math.h>

// SparseMLP: W=8 experts, per w: out = gelu(X @ W1 + b1) @ W2 + b2
// Round 7: GEMMs identical to Round 4 (best verified: 8-phase 256x256x64,
// 8 waves, counted vmcnt(4), XOR-swizzled LDS via pre-swizzled gload source,
// expert-to-XCD pinning). Prepass rebuilt: convert does 32B-in/16B-out per
// thread; both weight transposes + bias tail fused into ONE dispatch with a
// transposed-in-LDS layout (XOR swizzle (c&7)<<4; b128 reads, coalesced 16B
// global writes).

typedef float f32x4 __attribute__((ext_vector_type(4)));
typedef short bf16x8 __attribute__((ext_vector_type(8)));
typedef short bf16x4 __attribute__((ext_vector_type(4)));
typedef unsigned short u16;

#define NW 8
#define MDIM 2048   // BHS*SEQ
#define HDIM 2048
#define FFN  1024

static __device__ __forceinline__ u16 f32_to_bf16_rn(float f) {
  union { float f; unsigned u; } v; v.f = f;
  unsigned r = v.u + 0x7FFF + ((v.u >> 16) & 1);
  return (u16)(r >> 16);
}

static __device__ __forceinline__ void gload_lds16(const void* g, void* l) {
  __builtin_amdgcn_global_load_lds(
      (const __attribute__((address_space(1))) void*)g,
      (__attribute__((address_space(3))) void*)l, 16, 0, 0);
}

// X (NW*MDIM*HDIM f32) -> bf16; 8 elems/thread (2x f32x4 in, 1x bf16x8 out)
__global__ void convert_bf16_kernel(const float* __restrict__ in,
                                    u16* __restrict__ out) {
  size_t i = (size_t)blockIdx.x * blockDim.x + threadIdx.x;  // bf16x8 unit
  f32x4 a = ((const f32x4*)in)[2 * i];
  f32x4 b = ((const f32x4*)in)[2 * i + 1];
  bf16x8 p;
  p[0] = (short)f32_to_bf16_rn(a.x); p[1] = (short)f32_to_bf16_rn(a.y);
  p[2] = (short)f32_to_bf16_rn(a.z); p[3] = (short)f32_to_bf16_rn(a.w);
  p[4] = (short)f32_to_bf16_rn(b.x); p[5] = (short)f32_to_bf16_rn(b.y);
  p[6] = (short)f32_to_bf16_rn(b.z); p[7] = (short)f32_to_bf16_rn(b.w);
  ((bf16x8*)out)[i] = p;
}

// Fused weight prep: blocks [0,2048): w1 (R=2048,C=1024) -> W1t (C,R) bf16;
// [2048,4096): w2 (R=1024,C=2048) -> W2t; [4096,4112): out_bias copy.
// Per block: 64(r) x 128(c) tile. LDS holds the tile TRANSPOSED: element
// (r,c) at byte c*128 + ((2r) ^ ((c&7)<<4)). Store: 4-way bank alias (ok).
// Read: b128 = rows r8..r8+7 of column c, contiguous (XOR preserves 16B
// blocks). Global write: 16 B/lane, 8 lanes = 128B contiguous per column.
__global__ void prep_weights_kernel(const float* __restrict__ w1,
                                    const float* __restrict__ w2,
                                    const float* __restrict__ b2,
                                    u16* __restrict__ W1t,
                                    u16* __restrict__ W2t,
                                    float* __restrict__ outb) {
  int bid = blockIdx.x;
  int t = threadIdx.x;  // 256
  if (bid >= 4096) {  // bias tail: 16 blocks x 256 thr x 4 f32
    size_t i = (size_t)(bid - 4096) * 256 + t;
    ((f32x4*)outb)[i] = ((const f32x4*)b2)[i];
    return;
  }
  int R, C, nCB;
  const float* ip;
  u16* op;
  if (bid < 2048) { R = HDIM; C = FFN; nCB = FFN / 128; ip = w1; op = W1t; }
  else { bid -= 2048; R = FFN; C = HDIM; nCB = HDIM / 128; ip = w2; op = W2t; }
  const int nRB = (R / 64);
  const int cb = bid % nCB, rb = (bid / nCB) % nRB, w = bid / (nCB * nRB);
  const int r0 = rb * 64, c0 = cb * 128;
  ip += (size_t)w * R * C;
  op += (size_t)w * C * R;

  __shared__ __align__(16) char ldsT[16384];  // 128 cols x 128B (64 rows bf16)

  const int rr = t >> 5;          // 0..7
  const int c4 = (t & 31) * 4;    // 0..124
#pragma unroll
  for (int it = 0; it < 8; ++it) {
    int r = rr + it * 8;
    f32x4 v = *(const f32x4*)(ip + (size_t)(r0 + r) * C + c0 + c4);
#pragma unroll
    for (int e = 0; e < 4; ++e) {
      int c = c4 + e;
      float f = (e == 0) ? v.x : (e == 1) ? v.y : (e == 2) ? v.z : v.w;
      *(u16*)(ldsT + c * 128 + ((2 * r) ^ ((c & 7) << 4))) = f32_to_bf16_rn(f);
    }
  }
  __syncthreads();
  const int r16 = (t & 7) * 16;   // byte offset of 8-row group
  const int cc = t >> 3;          // 0..31
#pragma unroll
  for (int it = 0; it < 4; ++it) {
    int c = cc + it * 32;
    bf16x8 v = *(const bf16x8*)(ldsT + c * 128 + (r16 ^ ((c & 7) << 4)));
    *(bf16x8*)(op + (size_t)(c0 + c) * R + r0 + (r16 >> 1)) = v;
  }
}

// ---------------- GEMM (identical to Round 4) ----------------
// LDS layout per K-tile buffer (64KB): A0 @0, A1 @16384, B0 @32768, B1 @49152
#define STAGE_AH(dst, tt, h)                                                  \
  do {                                                                        \
    gload_lds16(gA + (size_t)(h) * 128 * rowK + (size_t)(tt) * 128,           \
                (dst) + (h) * 16384 + tid * 16);                              \
    gload_lds16(gA + ((size_t)(h) * 128 + 64) * rowK + (size_t)(tt) * 128,    \
                (dst) + (h) * 16384 + 8192 + tid * 16);                       \
  } while (0)
#define STAGE_BH(dst, tt, h)                                                  \
  do {                                                                        \
    gload_lds16(gB + (size_t)(h) * 128 * rowK + (size_t)(tt) * 128,           \
                (dst) + 32768 + (h) * 16384 + tid * 16);                      \
    gload_lds16(gB + ((size_t)(h) * 128 + 64) * rowK + (size_t)(tt) * 128,    \
                (dst) + 32768 + (h) * 16384 + 8192 + tid * 16);               \
  } while (0)

#define DO_PHASE(SB, q, first, STAGES, VMCODE)                                \
  {                                                                           \
    if (first) {                                                              \
      _Pragma("unroll") for (int jj = 0; jj < 4; ++jj)                        \
          _Pragma("unroll") for (int kk = 0; kk < 2; ++kk)                    \
              bfr[jj][kk] = *(const bf16x8*)((SB) + Boff +                    \
                  (brow + jj * 16 + ra) * 128 + (colsw ^ (kk << 6)));         \
    }                                                                         \
    _Pragma("unroll") for (int ii = 0; ii < 2; ++ii)                          \
        _Pragma("unroll") for (int kk = 0; kk < 2; ++kk)                      \
            afr[ii][kk] = *(const bf16x8*)((SB) + Aoff +                      \
                ((q)*32 + ii * 16 + ra) * 128 + (colsw ^ (kk << 6)));         \
    STAGES;                                                                   \
    __builtin_amdgcn_s_barrier();                                             \
    asm volatile("s_waitcnt lgkmcnt(0)" ::: "memory");                        \
    __builtin_amdgcn_sched_barrier(0);                                        \
    __builtin_amdgcn_s_setprio(1);                                            \
    _Pragma("unroll") for (int ii = 0; ii < 2; ++ii)                          \
        _Pragma("unroll") for (int jj = 0; jj < 4; ++jj)                      \
            _Pragma("unroll") for (int kk = 0; kk < 2; ++kk)                  \
                acc[(q)*2 + ii][jj] =                                         \
                    __builtin_amdgcn_mfma_f32_16x16x32_bf16(                  \
                        afr[ii][kk], bfr[jj][kk], acc[(q)*2 + ii][jj],        \
                        0, 0, 0);                                             \
    __builtin_amdgcn_s_setprio(0);                                            \
    VMCODE;                                                                   \
    __builtin_amdgcn_s_barrier();                                             \
  }

template <bool GELU, bool C_F32>
__global__ __launch_bounds__(512, 2) void mlp_gemm(
    const u16* __restrict__ A, const u16* __restrict__ Bt,
    const float* __restrict__ bias, void* __restrict__ Cptr,
    int M, int N, int K, int nN) {
  __shared__ __align__(16) char lds[131072];
  char* cur = lds;
  char* nxt = lds + 65536;

  const int bid = blockIdx.x;
  const int w = bid & 7;            // expert -> pinned to XCD bid%8
  const int jb = bid >> 3;
  const int m0 = (jb / nN) * 256;
  const int n0 = (jb % nN) * 256;

  const int tid = threadIdx.x;
  const int wid = tid >> 6, lane = tid & 63;
  const int wr = wid >> 2, wc = wid & 3;   // 2 M-waves x 4 N-waves
  const int qa = lane >> 4, ra = lane & 15;

  const u16* ap = A + (size_t)w * M * K;
  const u16* btp = Bt + (size_t)w * N * K;
  const float* bp = bias + (size_t)w * N;

  const size_t rowK = (size_t)K * 2;
  const int r8 = tid >> 3;
  const int csw = ((tid & 7) * 16) ^ ((r8 & 7) << 4);
  const char* gA = (const char*)ap + (size_t)(m0 + r8) * rowK + csw;
  const char* gB = (const char*)btp + (size_t)(n0 + r8) * rowK + csw;

  const int colsw = (qa * 16) ^ ((ra & 7) << 4);
  const int Aoff = wr * 16384;
  const int Boff = 32768 + (wc >> 1) * 16384;
  const int brow = (wc & 1) * 64;

  f32x4 acc[8][4];
#pragma unroll
  for (int i = 0; i < 8; ++i)
#pragma unroll
    for (int j = 0; j < 4; ++j)
#pragma unroll
      for (int r = 0; r < 4; ++r) acc[i][j][r] = 0.0f;

  const int NT = K >> 6;
  const int nIter = NT >> 1;

  STAGE_BH(cur, 0, 0); STAGE_BH(cur, 0, 1);
  STAGE_AH(cur, 0, 0); STAGE_AH(cur, 0, 1);
  STAGE_BH(nxt, 1, 0); STAGE_BH(nxt, 1, 1);
  asm volatile("s_waitcnt vmcnt(4)" ::: "memory");
  __builtin_amdgcn_sched_barrier(0);
  __builtin_amdgcn_s_barrier();

  bf16x8 bfr[4][2], afr[2][2];
  for (int it = 0; it < nIter; ++it) {
    const int t = it * 2;
    const bool s2 = (t + 2) < NT, s3 = (t + 3) < NT;

    DO_PHASE(cur, 0, 1, { STAGE_AH(nxt, t + 1, 0); }, {});
    DO_PHASE(cur, 1, 0,
             { STAGE_AH(nxt, t + 1, 1); if (s2) STAGE_BH(cur, t + 2, 0); }, {});
    DO_PHASE(cur, 2, 0, { if (s2) STAGE_BH(cur, t + 2, 1); }, {});
    DO_PHASE(cur, 3, 0, {}, {
      if (s2) asm volatile("s_waitcnt vmcnt(4)" ::: "memory");
      else    asm volatile("s_waitcnt vmcnt(0)" ::: "memory");
      __builtin_amdgcn_sched_barrier(0);
    });
    DO_PHASE(nxt, 0, 1, { if (s2) STAGE_AH(cur, t + 2, 0); }, {});
    DO_PHASE(nxt, 1, 0,
             { if (s2) STAGE_AH(cur, t + 2, 1); if (s3) STAGE_BH(nxt, t + 3, 0); }, {});
    DO_PHASE(nxt, 2, 0, { if (s3) STAGE_BH(nxt, t + 3, 1); }, {});
    DO_PHASE(nxt, 3, 0, {}, {
      if (s3) asm volatile("s_waitcnt vmcnt(4)" ::: "memory");
      else    asm volatile("s_waitcnt vmcnt(0)" ::: "memory");
      __builtin_amdgcn_sched_barrier(0);
    });
  }

#pragma unroll
  for (int i = 0; i < 8; ++i) {
#pragma unroll
    for (int j = 0; j < 4; ++j) {
      int col = n0 + wc * 64 + j * 16 + ra;
      float bv = bp[col];
#pragma unroll
      for (int r = 0; r < 4; ++r) {
        int row = m0 + wr * 128 + i * 16 + qa * 4 + r;
        float v = acc[i][j][r] + bv;
        if (GELU) v = 0.5f * v * (1.0f + erff(v * 0.70710678118654752f));
        if (C_F32)
          ((float*)Cptr)[(size_t)w * M * N + (size_t)row * N + col] = v;
        else
          ((u16*)Cptr)[(size_t)w * M * N + (size_t)row * N + col] =
              f32_to_bf16_rn(v);
      }
    }
  }
}

extern "C" void kernel_launch(void* const* d_in, const int* in_sizes, int n_in,
                              void* d_out, int out_size, void* d_ws,
                              size_t ws_size, hipStream_t stream) {
  const float* hs = (const float*)d_in[0];  // (8,2,1024,2048) f32
  const float* w1 = (const float*)d_in[1];  // (8,2048,1024) f32
  const float* b1 = (const float*)d_in[2];  // (8,1,1024) f32
  const float* w2 = (const float*)d_in[3];  // (8,1024,2048) f32
  const float* b2 = (const float*)d_in[4];  // (8,2048) f32

  // ws (u16): W1t (8,1024,2048) | W2t (8,2048,1024) | inter (8,2048,1024) | Xb (8,2048,2048)
  u16* W1t = (u16*)d_ws;
  u16* W2t = W1t + (size_t)NW * FFN * HDIM;
  u16* inter = W2t + (size_t)NW * HDIM * FFN;
  u16* XbWs = inter + (size_t)NW * MDIM * FFN;
  size_t need = ((size_t)NW * FFN * HDIM * 2 + (size_t)NW * MDIM * FFN +
                 (size_t)NW * MDIM * HDIM) * sizeof(u16);
  u16* Xb = (ws_size >= need) ? XbWs : (u16*)d_out;

  float* outb = (float*)d_out + (size_t)NW * MDIM * HDIM;

  // X -> bf16 (8 elems/thread)
  convert_bf16_kernel<<<dim3(NW * MDIM * HDIM / 8 / 256), 256, 0, stream>>>(hs, Xb);
  // fused: w1^T, w2^T (bf16) + out_bias tail
  prep_weights_kernel<<<dim3(4096 + 16), 256, 0, stream>>>(w1, w2, b2, W1t,
                                                           W2t, outb);

  // inter = gelu(X @ W1 + b1)  [bf16]  M=2048 N=1024 K=2048 -> 256 blocks
  mlp_gemm<true, false>
      <<<dim3(NW * (MDIM / 256) * (FFN / 256)), 512, 0, stream>>>(
          Xb, W1t, b1, inter, MDIM, FFN, HDIM, FFN / 256);
  // out = inter @ W2 + b2  [f32]  M=2048 N=2048 K=1024 -> 512 blocks
  mlp_gemm<false, true>
      <<<dim3(NW * (MDIM / 256) * (HDIM / 256)), 512, 0, stream>>>(
          inter, W2t, b2, d_out, MDIM, HDIM, FFN, HDIM / 256);
}

// Round 8
// 247.179 us; speedup vs baseline: 2.0054x; 1.1293x over previous
//
#include <hip/hip_runtime.h>
#include <hip/hip_bf16.h>
#include <math.h>

// SparseMLP: W=8 experts, per w: out = gelu(X @ W1 + b1) @ W2 + b2
// Round 8: R4 base (best verified: 8-phase 256x256x64, 8 waves, counted
// vmcnt(4), XOR-swizzled LDS via pre-swizzled gload source, expert->XCD
// pinning; R4 prep kernels restored verbatim). NEW: X f32->bf16 convert is
// FUSED into GEMM1's A-staging (T14 reg-stage: f32 loads issued ph1/ph5,
// cvt + ds_write_b128 at ph4/ph8 behind vmcnt(4)). vmcnt ledger (steady):
//   ph4: outstanding = B(t+1)[4] + Af32[8] + B(t+2)[4] = 16 -> vmcnt(4)
//        drains B(t+1)+A, leaves B(t+2); ds_writes drained by the existing
//        post-barrier lgkmcnt(0) before the consuming phase's end barrier.
// GEMM2 keeps the R4 gload_lds A-path (A_F32=false).

typedef float f32x4 __attribute__((ext_vector_type(4)));
typedef short bf16x8 __attribute__((ext_vector_type(8)));
typedef short bf16x4 __attribute__((ext_vector_type(4)));
typedef unsigned short u16;

#define NW 8
#define MDIM 2048   // BHS*SEQ
#define HDIM 2048
#define FFN  1024

static __device__ __forceinline__ u16 f32_to_bf16_rn(float f) {
  union { float f; unsigned u; } v; v.f = f;
  unsigned r = v.u + 0x7FFF + ((v.u >> 16) & 1);
  return (u16)(r >> 16);
}

static __device__ __forceinline__ void gload_lds16(const void* g, void* l) {
  __builtin_amdgcn_global_load_lds(
      (const __attribute__((address_space(1))) void*)g,
      (__attribute__((address_space(3))) void*)l, 16, 0, 0);
}

// in: (NW, R, C) f32 -> out: (NW, C, R) bf16 (convert + transpose), 64x64 tile
__global__ void convert_transpose_kernel(const float* __restrict__ in,
                                         u16* __restrict__ out, int R, int C) {
  __shared__ u16 tile[64][68];
  int w = blockIdx.z;
  int c0 = blockIdx.x * 64, r0 = blockIdx.y * 64;
  int t = threadIdx.x;  // 256 threads
  const float* ip = in + (size_t)w * R * C;
  u16* op = out + (size_t)w * C * R;
  int tr = t >> 4;       // 0..15
  int tc4 = (t & 15) * 4;
#pragma unroll
  for (int j = 0; j < 4; ++j) {
    int r = tr + j * 16;
    f32x4 v = *(const f32x4*)(ip + (size_t)(r0 + r) * C + c0 + tc4);
    tile[r][tc4 + 0] = f32_to_bf16_rn(v.x);
    tile[r][tc4 + 1] = f32_to_bf16_rn(v.y);
    tile[r][tc4 + 2] = f32_to_bf16_rn(v.z);
    tile[r][tc4 + 3] = f32_to_bf16_rn(v.w);
  }
  __syncthreads();
#pragma unroll
  for (int j = 0; j < 4; ++j) {
    int c = tr + j * 16;
    bf16x4 p;
    p[0] = (short)tile[tc4 + 0][c];
    p[1] = (short)tile[tc4 + 1][c];
    p[2] = (short)tile[tc4 + 2][c];
    p[3] = (short)tile[tc4 + 3][c];
    *(bf16x4*)(op + (size_t)(c0 + c) * R + r0 + tc4) = p;
  }
}

// ---------------- GEMM ----------------
// LDS layout per K-tile buffer (64KB): A0 @0, A1 @16384, B0 @32768, B1 @49152
#define STAGE_AH(dst, tt, h)                                                  \
  do {                                                                        \
    gload_lds16(gA + (size_t)(h) * 128 * rowK + (size_t)(tt) * 128,           \
                (dst) + (h) * 16384 + tid * 16);                              \
    gload_lds16(gA + ((size_t)(h) * 128 + 64) * rowK + (size_t)(tt) * 128,    \
                (dst) + (h) * 16384 + 8192 + tid * 16);                       \
  } while (0)
#define STAGE_BH(dst, tt, h)                                                  \
  do {                                                                        \
    gload_lds16(gB + (size_t)(h) * 128 * rowK + (size_t)(tt) * 128,           \
                (dst) + 32768 + (h) * 16384 + tid * 16);                      \
    gload_lds16(gB + ((size_t)(h) * 128 + 64) * rowK + (size_t)(tt) * 128,    \
                (dst) + 32768 + (h) * 16384 + 8192 + tid * 16);               \
  } while (0)

// A_F32 path: issue 8 f32x4 loads for A-tile tt (rows h*128+g*64+r8,
// f32 bytes [2*csw, 2*csw+32) -> same bf16 slots as gload path)
#define A_LOADS(tt)                                                           \
  _Pragma("unroll") for (int h_ = 0; h_ < 2; ++h_)                            \
  _Pragma("unroll") for (int g_ = 0; g_ < 2; ++g_)                            \
  _Pragma("unroll") for (int j_ = 0; j_ < 2; ++j_)                            \
      ar[h_][g_][j_] = *(const f32x4*)(gAf +                                  \
          (size_t)(h_ * 128 + g_ * 64) * rowKf + (size_t)(tt) * 256 + j_ * 16)

#define A_WRITES(dst)                                                         \
  _Pragma("unroll") for (int h_ = 0; h_ < 2; ++h_)                            \
  _Pragma("unroll") for (int g_ = 0; g_ < 2; ++g_) {                          \
    bf16x8 p_;                                                                \
    _Pragma("unroll") for (int e_ = 0; e_ < 4; ++e_) {                        \
      p_[e_]     = (short)f32_to_bf16_rn(ar[h_][g_][0][e_]);                  \
      p_[e_ + 4] = (short)f32_to_bf16_rn(ar[h_][g_][1][e_]);                  \
    }                                                                         \
    *(bf16x8*)((dst) + h_ * 16384 + g_ * 8192 + tid * 16) = p_;               \
  }

#define DO_PHASE(SB, q, first, STAGES, VMCODE)                                \
  {                                                                           \
    if (first) {                                                              \
      _Pragma("unroll") for (int jj = 0; jj < 4; ++jj)                        \
          _Pragma("unroll") for (int kk = 0; kk < 2; ++kk)                    \
              bfr[jj][kk] = *(const bf16x8*)((SB) + Boff +                    \
                  (brow + jj * 16 + ra) * 128 + (colsw ^ (kk << 6)));         \
    }                                                                         \
    _Pragma("unroll") for (int ii = 0; ii < 2; ++ii)                          \
        _Pragma("unroll") for (int kk = 0; kk < 2; ++kk)                      \
            afr[ii][kk] = *(const bf16x8*)((SB) + Aoff +                      \
                ((q)*32 + ii * 16 + ra) * 128 + (colsw ^ (kk << 6)));         \
    STAGES;                                                                   \
    __builtin_amdgcn_s_barrier();                                             \
    asm volatile("s_waitcnt lgkmcnt(0)" ::: "memory");                        \
    __builtin_amdgcn_sched_barrier(0);                                        \
    __builtin_amdgcn_s_setprio(1);                                            \
    _Pragma("unroll") for (int ii = 0; ii < 2; ++ii)                          \
        _Pragma("unroll") for (int jj = 0; jj < 4; ++jj)                      \
            _Pragma("unroll") for (int kk = 0; kk < 2; ++kk)                  \
                acc[(q)*2 + ii][jj] =                                         \
                    __builtin_amdgcn_mfma_f32_16x16x32_bf16(                  \
                        afr[ii][kk], bfr[jj][kk], acc[(q)*2 + ii][jj],        \
                        0, 0, 0);                                             \
    __builtin_amdgcn_s_setprio(0);                                            \
    VMCODE;                                                                   \
    __builtin_amdgcn_s_barrier();                                             \
  }

template <bool A_F32, bool GELU, bool C_F32>
__global__ __launch_bounds__(512, 2) void mlp_gemm(
    const void* __restrict__ Aptr, const u16* __restrict__ Bt,
    const float* __restrict__ bias, void* __restrict__ Cptr,
    int M, int N, int K, int nN) {
  __shared__ __align__(16) char lds[131072];
  char* cur = lds;
  char* nxt = lds + 65536;

  const int bid = blockIdx.x;
  const int w = bid & 7;            // expert -> pinned to XCD bid%8
  const int jb = bid >> 3;
  const int m0 = (jb / nN) * 256;
  const int n0 = (jb % nN) * 256;

  const int tid = threadIdx.x;
  const int wid = tid >> 6, lane = tid & 63;
  const int wr = wid >> 2, wc = wid & 3;   // 2 M-waves x 4 N-waves
  const int qa = lane >> 4, ra = lane & 15;

  const u16* btp = Bt + (size_t)w * N * K;
  const float* bp = bias + (size_t)w * N;

  const size_t rowK = (size_t)K * 2;
  const size_t rowKf = (size_t)K * 4;
  const int r8 = tid >> 3;
  const int csw = ((tid & 7) * 16) ^ ((r8 & 7) << 4);
  // bf16 A source (A_F32=false)
  const char* gA = (const char*)((const u16*)Aptr + (size_t)w * M * K) +
                   (size_t)(m0 + r8) * rowK + csw;
  // f32 A source (A_F32=true): f32 byte offset = 2 * bf16 byte offset
  const char* gAf = (const char*)((const float*)Aptr + (size_t)w * M * K) +
                    (size_t)(m0 + r8) * rowKf + 2 * csw;
  const char* gB = (const char*)btp + (size_t)(n0 + r8) * rowK + csw;

  const int colsw = (qa * 16) ^ ((ra & 7) << 4);
  const int Aoff = wr * 16384;
  const int Boff = 32768 + (wc >> 1) * 16384;
  const int brow = (wc & 1) * 64;

  f32x4 acc[8][4];
#pragma unroll
  for (int i = 0; i < 8; ++i)
#pragma unroll
    for (int j = 0; j < 4; ++j)
#pragma unroll
      for (int r = 0; r < 4; ++r) acc[i][j][r] = 0.0f;

  const int NT = K >> 6;        // even for both GEMMs
  const int nIter = NT >> 1;

  bf16x8 bfr[4][2], afr[2][2];
  f32x4 ar[2][2][2];

  if (A_F32) {
    // prologue: A(0) f32 loads, B(0), B(1); drain A(0)+B(0); write A(0)
    A_LOADS(0);
    STAGE_BH(cur, 0, 0); STAGE_BH(cur, 0, 1);
    STAGE_BH(nxt, 1, 0); STAGE_BH(nxt, 1, 1);
    asm volatile("s_waitcnt vmcnt(4)" ::: "memory");  // A(0)+B(0) landed
    A_WRITES(cur);
    asm volatile("s_waitcnt lgkmcnt(0)" ::: "memory");
    __builtin_amdgcn_sched_barrier(0);
    __builtin_amdgcn_s_barrier();

    for (int it = 0; it < nIter; ++it) {
      const int t = it * 2;
      const bool s2 = (t + 2) < NT;   // NT even => s3 == s2

      DO_PHASE(cur, 0, 1, { A_LOADS(t + 1); }, {});
      DO_PHASE(cur, 1, 0, { if (s2) STAGE_BH(cur, t + 2, 0); }, {});
      DO_PHASE(cur, 2, 0, { if (s2) STAGE_BH(cur, t + 2, 1); }, {});
      DO_PHASE(cur, 3, 0, {
        if (s2) asm volatile("s_waitcnt vmcnt(4)" ::: "memory");
        else    asm volatile("s_waitcnt vmcnt(0)" ::: "memory");
        A_WRITES(nxt);                 // A(t+1) -> nxt, visible after barrier
      }, {});
      DO_PHASE(nxt, 0, 1, { if (s2) A_LOADS(t + 2); }, {});
      DO_PHASE(nxt, 1, 0, { if (s2) STAGE_BH(nxt, t + 3, 0); }, {});
      DO_PHASE(nxt, 2, 0, { if (s2) STAGE_BH(nxt, t + 3, 1); }, {});
      DO_PHASE(nxt, 3, 0, {
        if (s2) {
          asm volatile("s_waitcnt vmcnt(4)" ::: "memory");
          A_WRITES(cur);               // A(t+2) -> cur
        }
      }, {});
    }
  } else {
    STAGE_BH(cur, 0, 0); STAGE_BH(cur, 0, 1);
    STAGE_AH(cur, 0, 0); STAGE_AH(cur, 0, 1);
    STAGE_BH(nxt, 1, 0); STAGE_BH(nxt, 1, 1);
    asm volatile("s_waitcnt vmcnt(4)" ::: "memory");
    __builtin_amdgcn_sched_barrier(0);
    __builtin_amdgcn_s_barrier();

    for (int it = 0; it < nIter; ++it) {
      const int t = it * 2;
      const bool s2 = (t + 2) < NT, s3 = (t + 3) < NT;

      DO_PHASE(cur, 0, 1, { STAGE_AH(nxt, t + 1, 0); }, {});
      DO_PHASE(cur, 1, 0,
               { STAGE_AH(nxt, t + 1, 1); if (s2) STAGE_BH(cur, t + 2, 0); }, {});
      DO_PHASE(cur, 2, 0, { if (s2) STAGE_BH(cur, t + 2, 1); }, {});
      DO_PHASE(cur, 3, 0, {}, {
        if (s2) asm volatile("s_waitcnt vmcnt(4)" ::: "memory");
        else    asm volatile("s_waitcnt vmcnt(0)" ::: "memory");
        __builtin_amdgcn_sched_barrier(0);
      });
      DO_PHASE(nxt, 0, 1, { if (s2) STAGE_AH(cur, t + 2, 0); }, {});
      DO_PHASE(nxt, 1, 0,
               { if (s2) STAGE_AH(cur, t + 2, 1); if (s3) STAGE_BH(nxt, t + 3, 0); }, {});
      DO_PHASE(nxt, 2, 0, { if (s3) STAGE_BH(nxt, t + 3, 1); }, {});
      DO_PHASE(nxt, 3, 0, {}, {
        if (s3) asm volatile("s_waitcnt vmcnt(4)" ::: "memory");
        else    asm volatile("s_waitcnt vmcnt(0)" ::: "memory");
        __builtin_amdgcn_sched_barrier(0);
      });
    }
  }

  // epilogue: + bias, optional exact GELU, store
#pragma unroll
  for (int i = 0; i < 8; ++i) {
#pragma unroll
    for (int j = 0; j < 4; ++j) {
      int col = n0 + wc * 64 + j * 16 + ra;
      float bv = bp[col];
#pragma unroll
      for (int r = 0; r < 4; ++r) {
        int row = m0 + wr * 128 + i * 16 + qa * 4 + r;
        float v = acc[i][j][r] + bv;
        if (GELU) v = 0.5f * v * (1.0f + erff(v * 0.70710678118654752f));
        if (C_F32)
          ((float*)Cptr)[(size_t)w * M * N + (size_t)row * N + col] = v;
        else
          ((u16*)Cptr)[(size_t)w * M * N + (size_t)row * N + col] =
              f32_to_bf16_rn(v);
      }
    }
  }
}

__global__ void bias_out_kernel(const float* __restrict__ b2,
                                float* __restrict__ outb) {
  int i = blockIdx.x * 256 + threadIdx.x;
  if (i < NW * HDIM) outb[i] = b2[i];
}

extern "C" void kernel_launch(void* const* d_in, const int* in_sizes, int n_in,
                              void* d_out, int out_size, void* d_ws,
                              size_t ws_size, hipStream_t stream) {
  const float* hs = (const float*)d_in[0];  // (8,2,1024,2048) f32
  const float* w1 = (const float*)d_in[1];  // (8,2048,1024) f32
  const float* b1 = (const float*)d_in[2];  // (8,1,1024) f32
  const float* w2 = (const float*)d_in[3];  // (8,1024,2048) f32
  const float* b2 = (const float*)d_in[4];  // (8,2048) f32

  // ws (u16): W1t (8,1024,2048) | W2t (8,2048,1024) | inter (8,2048,1024)
  u16* W1t = (u16*)d_ws;
  u16* W2t = W1t + (size_t)NW * FFN * HDIM;
  u16* inter = W2t + (size_t)NW * HDIM * FFN;

  // w1 (R=HDIM, C=FFN) -> W1t (FFN, HDIM)
  convert_transpose_kernel<<<dim3(FFN / 64, HDIM / 64, NW), 256, 0, stream>>>(
      w1, W1t, HDIM, FFN);
  // w2 (R=FFN, C=HDIM) -> W2t (HDIM, FFN)
  convert_transpose_kernel<<<dim3(HDIM / 64, FFN / 64, NW), 256, 0, stream>>>(
      w2, W2t, FFN, HDIM);

  // inter = gelu(X @ W1 + b1)  [bf16]  A = X in f32, cvt fused into staging
  mlp_gemm<true, true, false>
      <<<dim3(NW * (MDIM / 256) * (FFN / 256)), 512, 0, stream>>>(
          hs, W1t, b1, inter, MDIM, FFN, HDIM, FFN / 256);
  // out = inter @ W2 + b2  [f32]  A = inter bf16 (gload_lds path)
  mlp_gemm<false, false, true>
      <<<dim3(NW * (MDIM / 256) * (HDIM / 256)), 512, 0, stream>>>(
          inter, W2t, b2, d_out, MDIM, HDIM, FFN, HDIM / 256);

  float* outb = (float*)d_out + (size_t)NW * MDIM * HDIM;
  bias_out_kernel<<<dim3((NW * HDIM + 255) / 256), 256, 0, stream>>>(b2, outb);
}